// Round 1
// baseline (1728.974 us; speedup 1.0000x reference)
//
#include <hip/hip_runtime.h>
#include <hip/hip_bf16.h>

#define SEQL 4096
#define DCH  1024
#define BATCH 4
#define NFFT 8192
#define LOG2N 13
#define KFP (NFFT/2 + 1)   // 4097 stored spectrum entries per channel

// ---------------- MLP: h[l][16] ----------------
__global__ __launch_bounds__(256) void mlp_kernel(
        const float* __restrict__ z, const float* __restrict__ w1,
        const float* __restrict__ b1, float* __restrict__ h) {
    int l = blockIdx.x * blockDim.x + threadIdx.x;
    if (l >= SEQL) return;
    float pe0 = z[l * 3 + 0], pe1 = z[l * 3 + 1], pe2 = z[l * 3 + 2];
#pragma unroll
    for (int j = 0; j < 16; ++j) {
        float v = pe0 * w1[j * 3 + 0] + pe1 * w1[j * 3 + 1] + pe2 * w1[j * 3 + 2] + b1[j];
        h[l * 16 + j] = v > 0.f ? v : 0.f;
    }
}

// ---------------- transpose u (B,L,D) -> ut (B,D,L) ----------------
__global__ __launch_bounds__(256) void transpose_kernel(
        const float* __restrict__ u, float* __restrict__ ut) {
    __shared__ float tile[32][33];
    int b = blockIdx.z;
    int l0 = blockIdx.x * 32;
    int d0 = blockIdx.y * 32;
    int tx = threadIdx.x, ty = threadIdx.y;  // 32 x 8
    const float* up = u + (size_t)b * SEQL * DCH;
#pragma unroll
    for (int i = 0; i < 32; i += 8)
        tile[ty + i][tx] = up[(size_t)(l0 + ty + i) * DCH + d0 + tx];
    __syncthreads();
    float* utp = ut + (size_t)b * DCH * SEQL;
#pragma unroll
    for (int i = 0; i < 32; i += 8)
        utp[(size_t)(d0 + ty + i) * SEQL + l0 + tx] = tile[tx][ty + i];
}

// ---------------- in-place radix-2 FFT on LDS, 256 threads ----------------
template <int SIGN>
__device__ void fft8192_lds(float* re, float* im) {
    const int tid = threadIdx.x;
    const int NT = 256;
    // bit reversal
    for (int i = tid; i < NFFT; i += NT) {
        int r = (int)(__brev((unsigned)i) >> (32 - LOG2N));
        if (r > i) {
            float t;
            t = re[i]; re[i] = re[r]; re[r] = t;
            t = im[i]; im[i] = im[r]; im[r] = t;
        }
    }
    __syncthreads();
    for (int s = 1; s <= LOG2N; ++s) {
        const int half = 1 << (s - 1);
        const float angstep = SIGN * 6.283185307179586f / (float)(1 << s);
        for (int j = tid; j < NFFT / 2; j += NT) {
            int k = j & (half - 1);
            int g = j >> (s - 1);
            int i1 = (g << s) + k;
            int i2 = i1 + half;
            float sn, cs;
            sincosf(angstep * (float)k, &sn, &cs);
            float xr = re[i2], xi = im[i2];
            float tr = cs * xr - sn * xi;
            float ti = cs * xi + sn * xr;
            float ur = re[i1], ui = im[i1];
            re[i2] = ur - tr; im[i2] = ui - ti;
            re[i1] = ur + tr; im[i1] = ui + ti;
        }
        __syncthreads();
    }
}

// ---------------- filter row + forward FFT -> kf (half spectrum, /N) ----------------
__global__ __launch_bounds__(256) void filt_fft_kernel(
        const float* __restrict__ h, const float* __restrict__ w2,
        const float* __restrict__ b2, float2* __restrict__ kf) {
    __shared__ float re[NFFT];
    __shared__ float im[NFFT];
    int d = blockIdx.x;
    int tid = threadIdx.x;
    float w[16];
#pragma unroll
    for (int j = 0; j < 16; ++j) w[j] = w2[d * 16 + j];
    float bb = b2[d];
    for (int l = tid; l < SEQL; l += 256) {
        const float* hp = h + l * 16;
        float acc = bb;
#pragma unroll
        for (int j = 0; j < 16; ++j) acc += hp[j] * w[j];
        re[l] = acc; im[l] = 0.f;
    }
    for (int l = SEQL + tid; l < NFFT; l += 256) { re[l] = 0.f; im[l] = 0.f; }
    __syncthreads();
    fft8192_lds<-1>(re, im);
    const float scale = 1.f / (float)NFFT;
    for (int k = tid; k < KFP; k += 256)
        kf[(size_t)d * KFP + k] = make_float2(re[k] * scale, im[k] * scale);
}

// ---------------- per-row conv: FFT -> multiply -> inverse FFT (in place) ----------------
__global__ __launch_bounds__(256) void conv_kernel(
        float* __restrict__ uty, const float2* __restrict__ kf) {
    __shared__ float re[NFFT];
    __shared__ float im[NFFT];
    int row = blockIdx.x;           // b*DCH + d
    int d = row & (DCH - 1);
    int tid = threadIdx.x;
    float* rp = uty + (size_t)row * SEQL;
    for (int i = tid; i < SEQL; i += 256) { re[i] = rp[i]; im[i] = 0.f; }
    for (int i = SEQL + tid; i < NFFT; i += 256) { re[i] = 0.f; im[i] = 0.f; }
    __syncthreads();
    fft8192_lds<-1>(re, im);
    const float2* kfd = kf + (size_t)d * KFP;
    for (int k = tid; k < NFFT; k += 256) {
        float2 kv;
        if (k <= NFFT / 2) kv = kfd[k];
        else { float2 t = kfd[NFFT - k]; kv = make_float2(t.x, -t.y); }
        float ur = re[k], ui = im[k];
        re[k] = ur * kv.x - ui * kv.y;
        im[k] = ur * kv.y + ui * kv.x;
    }
    __syncthreads();
    fft8192_lds<1>(re, im);   // unscaled inverse DFT
    for (int i = tid; i < SEQL; i += 256) rp[i] = re[i];
}

// ---------------- fused GEMM (u @ pw^T + pb) * y + u ----------------
__global__ __launch_bounds__(256) void gemm_final_kernel(
        const float* __restrict__ u, const float* __restrict__ pw,
        const float* __restrict__ pb, const float* __restrict__ y,
        float* __restrict__ out) {
    __shared__ float As[16][64];
    __shared__ float Bs[16][64];
    __shared__ float ys[64][65];
    int n0 = blockIdx.x * 64;
    int m0 = blockIdx.y * 64;
    int tid = threadIdx.x;
    int tx = tid & 15, ty = tid >> 4;
    float c[4][4] = {};
    int row = tid >> 2;   // 0..63
    int kq = tid & 3;     // 0..3
    for (int kt = 0; kt < DCH; kt += 16) {
        float4 av = *(const float4*)&u[(size_t)(m0 + row) * DCH + kt + kq * 4];
        float4 bv = *(const float4*)&pw[(size_t)(n0 + row) * DCH + kt + kq * 4];
        As[kq * 4 + 0][row] = av.x; As[kq * 4 + 1][row] = av.y;
        As[kq * 4 + 2][row] = av.z; As[kq * 4 + 3][row] = av.w;
        Bs[kq * 4 + 0][row] = bv.x; Bs[kq * 4 + 1][row] = bv.y;
        Bs[kq * 4 + 2][row] = bv.z; Bs[kq * 4 + 3][row] = bv.w;
        __syncthreads();
#pragma unroll
        for (int kk = 0; kk < 16; ++kk) {
            float a[4], b[4];
#pragma unroll
            for (int i = 0; i < 4; ++i) a[i] = As[kk][i * 16 + ty];
#pragma unroll
            for (int j = 0; j < 4; ++j) b[j] = Bs[kk][j * 16 + tx];
#pragma unroll
            for (int i = 0; i < 4; ++i)
#pragma unroll
                for (int j = 0; j < 4; ++j) c[i][j] += a[i] * b[j];
        }
        __syncthreads();
    }
    // stage conv-output tile (transposed) through LDS: ys[l_local][d_local]
    int b = m0 >> 12;        // m0 / SEQL
    int l0 = m0 & (SEQL - 1);
    for (int idx = tid; idx < 64 * 64; idx += 256) {
        int dl = idx >> 6, ll = idx & 63;
        ys[ll][dl] = y[((size_t)(b * DCH + n0 + dl) << 12) + l0 + ll];
    }
    __syncthreads();
#pragma unroll
    for (int i = 0; i < 4; ++i)
#pragma unroll
        for (int j = 0; j < 4; ++j) {
            int m = m0 + i * 16 + ty;
            int n = n0 + j * 16 + tx;
            float proj = c[i][j] + pb[n];
            out[(size_t)m * DCH + n] = ys[i * 16 + ty][j * 16 + tx] * proj + u[(size_t)m * DCH + n];
        }
}

extern "C" void kernel_launch(void* const* d_in, const int* in_sizes, int n_in,
                              void* d_out, int out_size, void* d_ws, size_t ws_size,
                              hipStream_t stream) {
    const float* u  = (const float*)d_in[0];
    const float* z  = (const float*)d_in[1];
    const float* w1 = (const float*)d_in[2];
    const float* b1 = (const float*)d_in[3];
    const float* w2 = (const float*)d_in[4];
    const float* b2 = (const float*)d_in[5];
    const float* pw = (const float*)d_in[6];
    const float* pb = (const float*)d_in[7];
    float* out = (float*)d_out;

    float* h   = (float*)d_ws;                          // 4096*16 f32 = 256 KB
    float* uty = (float*)((char*)d_ws + 262144);        // B*D*L f32 = 64 MB (ut, then y in place)
    float2* kf = (float2*)d_out;                        // 1024*4097 float2 = 33.5 MB (scratch in out)

    mlp_kernel<<<dim3((SEQL + 255) / 256), dim3(256), 0, stream>>>(z, w1, b1, h);
    transpose_kernel<<<dim3(SEQL / 32, DCH / 32, BATCH), dim3(32, 8), 0, stream>>>(u, uty);
    filt_fft_kernel<<<dim3(DCH), dim3(256), 0, stream>>>(h, w2, b2, kf);
    conv_kernel<<<dim3(BATCH * DCH), dim3(256), 0, stream>>>(uty, kf);
    gemm_final_kernel<<<dim3(DCH / 64, (BATCH * SEQL) / 64), dim3(256), 0, stream>>>(u, pw, pb, uty, out);
}

// Round 2
// 798.665 us; speedup vs baseline: 2.1648x; 2.1648x over previous
//
#include <hip/hip_runtime.h>
#include <hip/hip_bf16.h>

#define SEQL 4096
#define DCH  1024
#define BATCH 4
#define NC   4096        // complex FFT length (carries real length-8192 signal)
#define KH   4097        // stored half-spectrum entries per channel

typedef float2 cf;
__device__ __forceinline__ cf mkc(float x, float y){ return make_float2(x,y); }
__device__ __forceinline__ cf cadd(cf a, cf b){ return mkc(a.x+b.x, a.y+b.y); }
__device__ __forceinline__ cf csub(cf a, cf b){ return mkc(a.x-b.x, a.y-b.y); }
__device__ __forceinline__ cf cmul(cf a, cf b){ return mkc(a.x*b.x - a.y*b.y, a.x*b.y + a.y*b.x); }
__device__ __forceinline__ cf cconjf(cf a){ return mkc(a.x, -a.y); }
__device__ __forceinline__ cf addi(cf a, cf b){ return mkc(a.x - b.y, a.y + b.x); }  // a + i*b
__device__ __forceinline__ cf subi(cf a, cf b){ return mkc(a.x + b.y, a.y - b.x); }  // a - i*b
__device__ __forceinline__ int cpad(int i){ return i + (i >> 4); }                   // +1 cplx per 16
__device__ __forceinline__ int drev(int i){                                          // reverse 6 base-4 digits
    return ((i>>10)&3) | (((i>>8)&3)<<2) | (((i>>6)&3)<<4)
         | (((i>>4)&3)<<6) | (((i>>2)&3)<<8) | ((i&3)<<10);
}

// ---------------- twiddle tables ----------------
__global__ __launch_bounds__(256) void twiddle_init(cf* __restrict__ tw4, cf* __restrict__ tw8){
    int i = blockIdx.x*256 + threadIdx.x;   // 4096 total
    const double TWO_PI = 6.283185307179586476925286766559;
    double a4 = -TWO_PI * (double)i / 4096.0;
    double a8 = -TWO_PI * (double)i / 8192.0;
    tw4[i] = mkc((float)cos(a4), (float)sin(a4));
    tw8[i] = mkc((float)cos(a8), (float)sin(a8));
}

// ---------------- forward radix-4 DIF: natural in -> digit-reversed out ----------------
__device__ void fft_dif(cf* lds, const cf* __restrict__ tw){
    const int tid = threadIdx.x;
#pragma unroll
    for (int p = 0; p < 4; ++p) {
        const int lm = 10 - 2*p;          // log2(m): 10,8,6,4
        const int m  = 1 << lm;
        const int step = 1024 >> lm;
#pragma unroll
        for (int it = 0; it < 4; ++it) {
            int j = tid + (it << 8);
            int k = j & (m-1);
            int g = j >> lm;
            int i0 = (g << (lm+2)) + k;
            cf x0 = lds[cpad(i0)];
            cf x1 = lds[cpad(i0+m)];
            cf x2 = lds[cpad(i0+2*m)];
            cf x3 = lds[cpad(i0+3*m)];
            cf b0 = cadd(x0,x2), b1 = csub(x0,x2);
            cf b2 = cadd(x1,x3), b3 = csub(x1,x3);
            cf u0 = cadd(b0,b2);
            cf u2 = csub(b0,b2);
            cf u1 = subi(b1,b3);
            cf u3 = addi(b1,b3);
            int t1 = k*step;
            lds[cpad(i0)]     = u0;
            lds[cpad(i0+m)]   = cmul(u1, tw[t1]);
            lds[cpad(i0+2*m)] = cmul(u2, tw[2*t1]);
            lds[cpad(i0+3*m)] = cmul(u3, tw[3*t1]);
        }
        __syncthreads();
    }
    // fused m=4 and m=1 passes: each thread owns contiguous 16-complex chunk [16t,16t+16)
    {
        int base = 17*tid;   // cpad(16t) = 17t, contiguous for 16 entries
        cf v[16];
#pragma unroll
        for (int j=0;j<16;++j) v[j] = lds[base+j];
#pragma unroll
        for (int j=0;j<4;++j){   // m=4, L=16, k=j
            cf x0=v[j], x1=v[j+4], x2=v[j+8], x3=v[j+12];
            cf b0=cadd(x0,x2), b1=csub(x0,x2), b2=cadd(x1,x3), b3=csub(x1,x3);
            cf u0=cadd(b0,b2), u2=csub(b0,b2), u1=subi(b1,b3), u3=addi(b1,b3);
            v[j]    = u0;
            v[j+4]  = cmul(u1, tw[256*j]);
            v[j+8]  = cmul(u2, tw[512*j]);
            v[j+12] = cmul(u3, tw[768*j]);
        }
#pragma unroll
        for (int c=0;c<4;++c){   // m=1, L=4, twiddle-free
            cf x0=v[4*c], x1=v[4*c+1], x2=v[4*c+2], x3=v[4*c+3];
            cf b0=cadd(x0,x2), b1=csub(x0,x2), b2=cadd(x1,x3), b3=csub(x1,x3);
            v[4*c]   = cadd(b0,b2);
            v[4*c+1] = subi(b1,b3);
            v[4*c+2] = csub(b0,b2);
            v[4*c+3] = addi(b1,b3);
        }
#pragma unroll
        for (int j=0;j<16;++j) lds[base+j] = v[j];
        __syncthreads();
    }
}

// ---------------- inverse radix-4 DIT: digit-reversed in -> natural out (unscaled) ----------------
__device__ void fft_dit_inv(cf* lds, const cf* __restrict__ tw){
    const int tid = threadIdx.x;
    {   // fused m=1 and m=4 passes
        int base = 17*tid;
        cf v[16];
#pragma unroll
        for (int j=0;j<16;++j) v[j] = lds[base+j];
#pragma unroll
        for (int c=0;c<4;++c){   // m=1
            cf a0=v[4*c], a1=v[4*c+1], a2=v[4*c+2], a3=v[4*c+3];
            cf b0=cadd(a0,a2), b1=csub(a0,a2), b2=cadd(a1,a3), b3=csub(a1,a3);
            v[4*c]   = cadd(b0,b2);
            v[4*c+1] = addi(b1,b3);
            v[4*c+2] = csub(b0,b2);
            v[4*c+3] = subi(b1,b3);
        }
#pragma unroll
        for (int j=0;j<4;++j){   // m=4, L=16, k=j, conj twiddles applied to inputs
            cf a0=v[j];
            cf a1=cmul(v[j+4],  cconjf(tw[256*j]));
            cf a2=cmul(v[j+8],  cconjf(tw[512*j]));
            cf a3=cmul(v[j+12], cconjf(tw[768*j]));
            cf b0=cadd(a0,a2), b1=csub(a0,a2), b2=cadd(a1,a3), b3=csub(a1,a3);
            v[j]    = cadd(b0,b2);
            v[j+4]  = addi(b1,b3);
            v[j+8]  = csub(b0,b2);
            v[j+12] = subi(b1,b3);
        }
#pragma unroll
        for (int j=0;j<16;++j) lds[base+j] = v[j];
        __syncthreads();
    }
#pragma unroll
    for (int p = 0; p < 4; ++p) {
        const int lm = 4 + 2*p;           // m = 16,64,256,1024
        const int m  = 1 << lm;
        const int step = 1024 >> lm;
#pragma unroll
        for (int it = 0; it < 4; ++it) {
            int j = tid + (it << 8);
            int k = j & (m-1);
            int g = j >> lm;
            int i0 = (g << (lm+2)) + k;
            int t1 = k*step;
            cf a0 = lds[cpad(i0)];
            cf a1 = cmul(lds[cpad(i0+m)],   cconjf(tw[t1]));
            cf a2 = cmul(lds[cpad(i0+2*m)], cconjf(tw[2*t1]));
            cf a3 = cmul(lds[cpad(i0+3*m)], cconjf(tw[3*t1]));
            cf b0=cadd(a0,a2), b1=csub(a0,a2), b2=cadd(a1,a3), b3=csub(a1,a3);
            lds[cpad(i0)]     = cadd(b0,b2);
            lds[cpad(i0+m)]   = addi(b1,b3);
            lds[cpad(i0+2*m)] = csub(b0,b2);
            lds[cpad(i0+3*m)] = subi(b1,b3);
        }
        __syncthreads();
    }
}

// ---------------- MLP: h[l][16] ----------------
__global__ __launch_bounds__(256) void mlp_kernel(
        const float* __restrict__ z, const float* __restrict__ w1,
        const float* __restrict__ b1, float* __restrict__ h) {
    int l = blockIdx.x * blockDim.x + threadIdx.x;
    if (l >= SEQL) return;
    float pe0 = z[l * 3 + 0], pe1 = z[l * 3 + 1], pe2 = z[l * 3 + 2];
#pragma unroll
    for (int j = 0; j < 16; ++j) {
        float v = pe0 * w1[j * 3 + 0] + pe1 * w1[j * 3 + 1] + pe2 * w1[j * 3 + 2] + b1[j];
        h[l * 16 + j] = v > 0.f ? v : 0.f;
    }
}

// ---------------- transpose u (B,L,D) -> ut (B,D,L) ----------------
__global__ __launch_bounds__(256) void transpose_kernel(
        const float* __restrict__ u, float* __restrict__ ut) {
    __shared__ float tile[32][33];
    int b = blockIdx.z;
    int l0 = blockIdx.x * 32;
    int d0 = blockIdx.y * 32;
    int tx = threadIdx.x, ty = threadIdx.y;  // 32 x 8
    const float* up = u + (size_t)b * SEQL * DCH;
#pragma unroll
    for (int i = 0; i < 32; i += 8)
        tile[ty + i][tx] = up[(size_t)(l0 + ty + i) * DCH + d0 + tx];
    __syncthreads();
    float* utp = ut + (size_t)b * DCH * SEQL;
#pragma unroll
    for (int i = 0; i < 32; i += 8)
        utp[(size_t)(d0 + ty + i) * SEQL + l0 + tx] = tile[tx][ty + i];
}

// ---------------- filter row -> packed FFT -> H[d][0..4096] (scaled 1/8192) ----------------
__global__ __launch_bounds__(256) void filt_fft_kernel(
        const float* __restrict__ h, const float* __restrict__ w2,
        const float* __restrict__ b2, const cf* __restrict__ tw4,
        const cf* __restrict__ tw8, cf* __restrict__ kf) {
    __shared__ cf lds[4352];
    int d = blockIdx.x;
    int tid = threadIdx.x;
    float w[16];
#pragma unroll
    for (int j = 0; j < 16; ++j) w[j] = w2[d * 16 + j];
    float bb = b2[d];
    for (int n = tid; n < 2048; n += 256) {
        const float* h0 = h + (size_t)(2*n) * 16;
        float f0 = bb, f1 = bb;
#pragma unroll
        for (int j = 0; j < 16; ++j) { f0 += h0[j] * w[j]; f1 += h0[16 + j] * w[j]; }
        lds[cpad(n)] = mkc(f0, f1);
    }
    for (int n = 2048 + tid; n < 4096; n += 256) lds[cpad(n)] = mkc(0.f, 0.f);
    __syncthreads();
    fft_dif(lds, tw4);
    const float s = 1.f / 8192.f;
    cf* Hrow = kf + (size_t)d * KH;
    for (int k = tid; k < 2048; k += 256) {
        if (k == 0) {
            cf c0 = lds[cpad(0)];
            Hrow[0]    = mkc((c0.x + c0.y) * s, 0.f);
            Hrow[4096] = mkc((c0.x - c0.y) * s, 0.f);
            cf c2 = lds[cpad(drev(2048))];
            Hrow[2048] = mkc(c2.x * s, -c2.y * s);
        } else {
            int kk = 4096 - k;
            cf ck  = lds[cpad(drev(k))];
            cf ckk = lds[cpad(drev(kk))];
            cf cc = cconjf(ckk);
            cf E  = mkc(0.5f*(ck.x+cc.x), 0.5f*(ck.y+cc.y));
            cf Dd = csub(ck, cc);
            cf O  = mkc(0.5f*Dd.y, -0.5f*Dd.x);          // -i/2 * (ck - conj(ckk))
            cf wv = tw8[k];
            cf Xk  = cadd(E, cmul(wv, O));
            cf wp  = mkc(-wv.x, wv.y);                   // -conj(w) = W^(4096-k)
            cf Xkk = cadd(cconjf(E), cmul(wp, cconjf(O)));
            Hrow[k]  = mkc(Xk.x * s, Xk.y * s);
            Hrow[kk] = mkc(Xkk.x * s, Xkk.y * s);
        }
    }
}

// ---------------- conv: packed fwd FFT -> spectral multiply -> packed inv FFT ----------------
__global__ __launch_bounds__(256) void conv_kernel(
        float* __restrict__ uty, const cf* __restrict__ tw4,
        const cf* __restrict__ tw8, const cf* __restrict__ kf) {
    __shared__ cf lds[4352];
    int row = blockIdx.x;            // b*DCH + d
    int d = row & (DCH - 1);
    int tid = threadIdx.x;
    float* rp = uty + (size_t)row * SEQL;
    for (int n = tid; n < 2048; n += 256)
        lds[cpad(n)] = *(const float2*)&rp[2*n];
    for (int n = 2048 + tid; n < 4096; n += 256) lds[cpad(n)] = mkc(0.f, 0.f);
    __syncthreads();
    fft_dif(lds, tw4);
    const cf* Hrow = kf + (size_t)d * KH;
    for (int k = tid; k < 2048; k += 256) {
        if (k == 0) {
            // k = 0 and k = 2048 specials (all quantities real at DC/Nyquist of X)
            cf c0 = lds[cpad(0)];
            float X0 = c0.x + c0.y, X4 = c0.x - c0.y;
            cf H0 = Hrow[0], H4 = Hrow[4096];
            cf Y0 = mkc(X0 * H0.x, X0 * H0.y);
            cf Y4 = mkc(X4 * H4.x, X4 * H4.y);
            cf S  = cadd(Y0, Y4), Dd = csub(Y0, Y4);
            lds[cpad(0)] = addi(S, Dd);                  // Z0 = S + i*D
            int s2 = cpad(drev(2048));
            cf c2 = lds[s2];
            cf Y2 = cmul(cconjf(c2), Hrow[2048]);        // X[2048] = conj(C[2048])
            lds[s2] = mkc(2.f * Y2.x, -2.f * Y2.y);      // Z[2048] = 2*conj(Y)
        } else {
            int kk = 4096 - k;
            int sk = cpad(drev(k)), skk = cpad(drev(kk));
            cf ck = lds[sk], ckk = lds[skk];
            cf cc = cconjf(ckk);
            cf E  = mkc(0.5f*(ck.x+cc.x), 0.5f*(ck.y+cc.y));
            cf Dd = csub(ck, cc);
            cf O  = mkc(0.5f*Dd.y, -0.5f*Dd.x);
            cf wv = tw8[k];
            cf Xk  = cadd(E, cmul(wv, O));
            cf wp  = mkc(-wv.x, wv.y);
            cf Xkk = cadd(cconjf(E), cmul(wp, cconjf(O)));
            cf Yk  = cmul(Xk,  Hrow[k]);
            cf Ykk = cmul(Xkk, Hrow[kk]);
            // Zk = (Yk + conj(Ykk)) + i*conj(w)*(Yk - conj(Ykk))
            cf cy = cconjf(Ykk);
            cf S  = cadd(Yk, cy), D2 = csub(Yk, cy);
            cf Zk = addi(S, cmul(cconjf(wv), D2));
            // Zkk = (Ykk + conj(Yk)) - i*w*(Ykk - conj(Yk))
            cf cy2 = cconjf(Yk);
            cf S2  = cadd(Ykk, cy2), D3 = csub(Ykk, cy2);
            cf Zkk = subi(S2, cmul(wv, D3));
            lds[sk] = Zk; lds[skk] = Zkk;
        }
    }
    __syncthreads();
    fft_dit_inv(lds, tw4);
    for (int n = tid; n < 2048; n += 256) {
        cf v = lds[cpad(n)];
        *(float2*)&rp[2*n] = v;                          // y[2n], y[2n+1]
    }
}

// ---------------- fused GEMM (u @ pw^T + pb) * y + u ----------------
__global__ __launch_bounds__(256) void gemm_final_kernel(
        const float* __restrict__ u, const float* __restrict__ pw,
        const float* __restrict__ pb, const float* __restrict__ y,
        float* __restrict__ out) {
    __shared__ float As[16][64];
    __shared__ float Bs[16][64];
    __shared__ float ys[64][65];
    int n0 = blockIdx.x * 64;
    int m0 = blockIdx.y * 64;
    int tid = threadIdx.x;
    int tx = tid & 15, ty = tid >> 4;
    float c[4][4] = {};
    int row = tid >> 2;
    int kq = tid & 3;
    for (int kt = 0; kt < DCH; kt += 16) {
        float4 av = *(const float4*)&u[(size_t)(m0 + row) * DCH + kt + kq * 4];
        float4 bv = *(const float4*)&pw[(size_t)(n0 + row) * DCH + kt + kq * 4];
        As[kq * 4 + 0][row] = av.x; As[kq * 4 + 1][row] = av.y;
        As[kq * 4 + 2][row] = av.z; As[kq * 4 + 3][row] = av.w;
        Bs[kq * 4 + 0][row] = bv.x; Bs[kq * 4 + 1][row] = bv.y;
        Bs[kq * 4 + 2][row] = bv.z; Bs[kq * 4 + 3][row] = bv.w;
        __syncthreads();
#pragma unroll
        for (int kk = 0; kk < 16; ++kk) {
            float a[4], b[4];
#pragma unroll
            for (int i = 0; i < 4; ++i) a[i] = As[kk][i * 16 + ty];
#pragma unroll
            for (int j = 0; j < 4; ++j) b[j] = Bs[kk][j * 16 + tx];
#pragma unroll
            for (int i = 0; i < 4; ++i)
#pragma unroll
                for (int j = 0; j < 4; ++j) c[i][j] += a[i] * b[j];
        }
        __syncthreads();
    }
    int b = m0 >> 12;
    int l0 = m0 & (SEQL - 1);
    for (int idx = tid; idx < 64 * 64; idx += 256) {
        int dl = idx >> 6, ll = idx & 63;
        ys[ll][dl] = y[((size_t)(b * DCH + n0 + dl) << 12) + l0 + ll];
    }
    __syncthreads();
#pragma unroll
    for (int i = 0; i < 4; ++i)
#pragma unroll
        for (int j = 0; j < 4; ++j) {
            int m = m0 + i * 16 + ty;
            int n = n0 + j * 16 + tx;
            float proj = c[i][j] + pb[n];
            out[(size_t)m * DCH + n] = ys[i * 16 + ty][j * 16 + tx] * proj + u[(size_t)m * DCH + n];
        }
}

extern "C" void kernel_launch(void* const* d_in, const int* in_sizes, int n_in,
                              void* d_out, int out_size, void* d_ws, size_t ws_size,
                              hipStream_t stream) {
    const float* u  = (const float*)d_in[0];
    const float* z  = (const float*)d_in[1];
    const float* w1 = (const float*)d_in[2];
    const float* b1 = (const float*)d_in[3];
    const float* w2 = (const float*)d_in[4];
    const float* b2 = (const float*)d_in[5];
    const float* pw = (const float*)d_in[6];
    const float* pb = (const float*)d_in[7];
    float* out = (float*)d_out;

    float* h   = (float*)d_ws;                           // 256 KB
    float* uty = (float*)((char*)d_ws + 262144);         // 64 MB
    // scratch inside d_out (fully overwritten by gemm at the end):
    cf* kf  = (cf*)d_out;                                // 1024*4097*8B = 33.5 MB
    cf* tw4 = (cf*)((char*)d_out + (40u << 20));         // 32 KB
    cf* tw8 = tw4 + 4096;                                // 32 KB

    twiddle_init<<<dim3(16), dim3(256), 0, stream>>>(tw4, tw8);
    mlp_kernel<<<dim3(16), dim3(256), 0, stream>>>(z, w1, b1, h);
    transpose_kernel<<<dim3(SEQL / 32, DCH / 32, BATCH), dim3(32, 8), 0, stream>>>(u, uty);
    filt_fft_kernel<<<dim3(DCH), dim3(256), 0, stream>>>(h, w2, b2, tw4, tw8, kf);
    conv_kernel<<<dim3(BATCH * DCH), dim3(256), 0, stream>>>(uty, tw4, tw8, kf);
    gemm_final_kernel<<<dim3(DCH / 64, (BATCH * SEQL) / 64), dim3(256), 0, stream>>>(u, pw, pb, uty, out);
}

// Round 3
// 332.999 us; speedup vs baseline: 5.1921x; 2.3984x over previous
//
#include <hip/hip_runtime.h>
#include <hip/hip_bf16.h>

#define SEQL 4096
#define DCH  1024
#define BATCH 4
#define NC   4096        // complex FFT length (carries real length-8192 signal)
#define KH   4097        // stored half-spectrum entries per channel

typedef float2 cf;
__device__ __forceinline__ cf mkc(float x, float y){ return make_float2(x,y); }
__device__ __forceinline__ cf cadd(cf a, cf b){ return mkc(a.x+b.x, a.y+b.y); }
__device__ __forceinline__ cf csub(cf a, cf b){ return mkc(a.x-b.x, a.y-b.y); }
__device__ __forceinline__ cf cmul(cf a, cf b){ return mkc(a.x*b.x - a.y*b.y, a.x*b.y + a.y*b.x); }
__device__ __forceinline__ cf cconjf(cf a){ return mkc(a.x, -a.y); }
__device__ __forceinline__ cf addi(cf a, cf b){ return mkc(a.x - b.y, a.y + b.x); }  // a + i*b
__device__ __forceinline__ cf subi(cf a, cf b){ return mkc(a.x + b.y, a.y - b.x); }  // a - i*b
__device__ __forceinline__ int cpad(int i){ return i + (i >> 4); }                   // +1 cplx per 16
__device__ __forceinline__ int drev(int i){                                          // reverse 6 base-4 digits
    return ((i>>10)&3) | (((i>>8)&3)<<2) | (((i>>6)&3)<<4)
         | (((i>>4)&3)<<6) | (((i>>2)&3)<<8) | ((i&3)<<10);
}

// ---------------- twiddle tables ----------------
__global__ __launch_bounds__(256) void twiddle_init(cf* __restrict__ tw4, cf* __restrict__ tw8){
    int i = blockIdx.x*256 + threadIdx.x;   // 4096 total
    const double TWO_PI = 6.283185307179586476925286766559;
    double a4 = -TWO_PI * (double)i / 4096.0;
    double a8 = -TWO_PI * (double)i / 8192.0;
    tw4[i] = mkc((float)cos(a4), (float)sin(a4));
    tw8[i] = mkc((float)cos(a8), (float)sin(a8));
}

// ---------------- forward radix-4 DIF: natural in -> digit-reversed out ----------------
__device__ void fft_dif(cf* lds, const cf* __restrict__ tw){
    const int tid = threadIdx.x;
#pragma unroll
    for (int p = 0; p < 4; ++p) {
        const int lm = 10 - 2*p;          // log2(m): 10,8,6,4
        const int m  = 1 << lm;
        const int step = 1024 >> lm;
#pragma unroll
        for (int it = 0; it < 4; ++it) {
            int j = tid + (it << 8);
            int k = j & (m-1);
            int g = j >> lm;
            int i0 = (g << (lm+2)) + k;
            cf x0 = lds[cpad(i0)];
            cf x1 = lds[cpad(i0+m)];
            cf x2 = lds[cpad(i0+2*m)];
            cf x3 = lds[cpad(i0+3*m)];
            cf b0 = cadd(x0,x2), b1 = csub(x0,x2);
            cf b2 = cadd(x1,x3), b3 = csub(x1,x3);
            cf u0 = cadd(b0,b2);
            cf u2 = csub(b0,b2);
            cf u1 = subi(b1,b3);
            cf u3 = addi(b1,b3);
            int t1 = k*step;
            lds[cpad(i0)]     = u0;
            lds[cpad(i0+m)]   = cmul(u1, tw[t1]);
            lds[cpad(i0+2*m)] = cmul(u2, tw[2*t1]);
            lds[cpad(i0+3*m)] = cmul(u3, tw[3*t1]);
        }
        __syncthreads();
    }
    // fused m=4 and m=1 passes: each thread owns contiguous 16-complex chunk [16t,16t+16)
    {
        int base = 17*tid;   // cpad(16t) = 17t, contiguous for 16 entries
        cf v[16];
#pragma unroll
        for (int j=0;j<16;++j) v[j] = lds[base+j];
#pragma unroll
        for (int j=0;j<4;++j){   // m=4, L=16, k=j
            cf x0=v[j], x1=v[j+4], x2=v[j+8], x3=v[j+12];
            cf b0=cadd(x0,x2), b1=csub(x0,x2), b2=cadd(x1,x3), b3=csub(x1,x3);
            cf u0=cadd(b0,b2), u2=csub(b0,b2), u1=subi(b1,b3), u3=addi(b1,b3);
            v[j]    = u0;
            v[j+4]  = cmul(u1, tw[256*j]);
            v[j+8]  = cmul(u2, tw[512*j]);
            v[j+12] = cmul(u3, tw[768*j]);
        }
#pragma unroll
        for (int c=0;c<4;++c){   // m=1, L=4, twiddle-free
            cf x0=v[4*c], x1=v[4*c+1], x2=v[4*c+2], x3=v[4*c+3];
            cf b0=cadd(x0,x2), b1=csub(x0,x2), b2=cadd(x1,x3), b3=csub(x1,x3);
            v[4*c]   = cadd(b0,b2);
            v[4*c+1] = subi(b1,b3);
            v[4*c+2] = csub(b0,b2);
            v[4*c+3] = addi(b1,b3);
        }
#pragma unroll
        for (int j=0;j<16;++j) lds[base+j] = v[j];
        __syncthreads();
    }
}

// ---------------- inverse radix-4 DIT: digit-reversed in -> natural out (unscaled) ----------------
__device__ void fft_dit_inv(cf* lds, const cf* __restrict__ tw){
    const int tid = threadIdx.x;
    {   // fused m=1 and m=4 passes
        int base = 17*tid;
        cf v[16];
#pragma unroll
        for (int j=0;j<16;++j) v[j] = lds[base+j];
#pragma unroll
        for (int c=0;c<4;++c){   // m=1
            cf a0=v[4*c], a1=v[4*c+1], a2=v[4*c+2], a3=v[4*c+3];
            cf b0=cadd(a0,a2), b1=csub(a0,a2), b2=cadd(a1,a3), b3=csub(a1,a3);
            v[4*c]   = cadd(b0,b2);
            v[4*c+1] = addi(b1,b3);
            v[4*c+2] = csub(b0,b2);
            v[4*c+3] = subi(b1,b3);
        }
#pragma unroll
        for (int j=0;j<4;++j){   // m=4, L=16, k=j, conj twiddles applied to inputs
            cf a0=v[j];
            cf a1=cmul(v[j+4],  cconjf(tw[256*j]));
            cf a2=cmul(v[j+8],  cconjf(tw[512*j]));
            cf a3=cmul(v[j+12], cconjf(tw[768*j]));
            cf b0=cadd(a0,a2), b1=csub(a0,a2), b2=cadd(a1,a3), b3=csub(a1,a3);
            v[j]    = cadd(b0,b2);
            v[j+4]  = addi(b1,b3);
            v[j+8]  = csub(b0,b2);
            v[j+12] = subi(b1,b3);
        }
#pragma unroll
        for (int j=0;j<16;++j) lds[base+j] = v[j];
        __syncthreads();
    }
#pragma unroll
    for (int p = 0; p < 4; ++p) {
        const int lm = 4 + 2*p;           // m = 16,64,256,1024
        const int m  = 1 << lm;
        const int step = 1024 >> lm;
#pragma unroll
        for (int it = 0; it < 4; ++it) {
            int j = tid + (it << 8);
            int k = j & (m-1);
            int g = j >> lm;
            int i0 = (g << (lm+2)) + k;
            int t1 = k*step;
            cf a0 = lds[cpad(i0)];
            cf a1 = cmul(lds[cpad(i0+m)],   cconjf(tw[t1]));
            cf a2 = cmul(lds[cpad(i0+2*m)], cconjf(tw[2*t1]));
            cf a3 = cmul(lds[cpad(i0+3*m)], cconjf(tw[3*t1]));
            cf b0=cadd(a0,a2), b1=csub(a0,a2), b2=cadd(a1,a3), b3=csub(a1,a3);
            lds[cpad(i0)]     = cadd(b0,b2);
            lds[cpad(i0+m)]   = addi(b1,b3);
            lds[cpad(i0+2*m)] = csub(b0,b2);
            lds[cpad(i0+3*m)] = subi(b1,b3);
        }
        __syncthreads();
    }
}

// ---------------- MLP: h[l][16] ----------------
__global__ __launch_bounds__(256) void mlp_kernel(
        const float* __restrict__ z, const float* __restrict__ w1,
        const float* __restrict__ b1, float* __restrict__ h) {
    int l = blockIdx.x * blockDim.x + threadIdx.x;
    if (l >= SEQL) return;
    float pe0 = z[l * 3 + 0], pe1 = z[l * 3 + 1], pe2 = z[l * 3 + 2];
#pragma unroll
    for (int j = 0; j < 16; ++j) {
        float v = pe0 * w1[j * 3 + 0] + pe1 * w1[j * 3 + 1] + pe2 * w1[j * 3 + 2] + b1[j];
        h[l * 16 + j] = v > 0.f ? v : 0.f;
    }
}

// ---------------- transpose u (B,L,D) -> ut (B,D,L) ----------------
__global__ __launch_bounds__(256) void transpose_kernel(
        const float* __restrict__ u, float* __restrict__ ut) {
    __shared__ float tile[32][33];
    int b = blockIdx.z;
    int l0 = blockIdx.x * 32;
    int d0 = blockIdx.y * 32;
    int tx = threadIdx.x, ty = threadIdx.y;  // 32 x 8
    const float* up = u + (size_t)b * SEQL * DCH;
#pragma unroll
    for (int i = 0; i < 32; i += 8)
        tile[ty + i][tx] = up[(size_t)(l0 + ty + i) * DCH + d0 + tx];
    __syncthreads();
    float* utp = ut + (size_t)b * DCH * SEQL;
#pragma unroll
    for (int i = 0; i < 32; i += 8)
        utp[(size_t)(d0 + ty + i) * SEQL + l0 + tx] = tile[tx][ty + i];
}

// ---------------- filter row -> packed FFT -> H[d][0..4096] (scaled 1/8192) ----------------
__global__ __launch_bounds__(256) void filt_fft_kernel(
        const float* __restrict__ h, const float* __restrict__ w2,
        const float* __restrict__ b2, const cf* __restrict__ tw4,
        const cf* __restrict__ tw8, cf* __restrict__ kf) {
    __shared__ cf lds[4352];
    int d = blockIdx.x;
    int tid = threadIdx.x;
    float w[16];
#pragma unroll
    for (int j = 0; j < 16; ++j) w[j] = w2[d * 16 + j];
    float bb = b2[d];
    for (int n = tid; n < 2048; n += 256) {
        const float* h0 = h + (size_t)(2*n) * 16;
        float f0 = bb, f1 = bb;
#pragma unroll
        for (int j = 0; j < 16; ++j) { f0 += h0[j] * w[j]; f1 += h0[16 + j] * w[j]; }
        lds[cpad(n)] = mkc(f0, f1);
    }
    for (int n = 2048 + tid; n < 4096; n += 256) lds[cpad(n)] = mkc(0.f, 0.f);
    __syncthreads();
    fft_dif(lds, tw4);
    const float s = 1.f / 8192.f;
    cf* Hrow = kf + (size_t)d * KH;
    for (int k = tid; k < 2048; k += 256) {
        if (k == 0) {
            cf c0 = lds[cpad(0)];
            Hrow[0]    = mkc((c0.x + c0.y) * s, 0.f);
            Hrow[4096] = mkc((c0.x - c0.y) * s, 0.f);
            cf c2 = lds[cpad(drev(2048))];
            Hrow[2048] = mkc(c2.x * s, -c2.y * s);
        } else {
            int kk = 4096 - k;
            cf ck  = lds[cpad(drev(k))];
            cf ckk = lds[cpad(drev(kk))];
            cf cc = cconjf(ckk);
            cf E  = mkc(0.5f*(ck.x+cc.x), 0.5f*(ck.y+cc.y));
            cf Dd = csub(ck, cc);
            cf O  = mkc(0.5f*Dd.y, -0.5f*Dd.x);          // -i/2 * (ck - conj(ckk))
            cf wv = tw8[k];
            cf Xk  = cadd(E, cmul(wv, O));
            cf wp  = mkc(-wv.x, wv.y);                   // -conj(w) = W^(4096-k)
            cf Xkk = cadd(cconjf(E), cmul(wp, cconjf(O)));
            Hrow[k]  = mkc(Xk.x * s, Xk.y * s);
            Hrow[kk] = mkc(Xkk.x * s, Xkk.y * s);
        }
    }
}

// ---------------- conv: packed fwd FFT -> spectral multiply -> packed inv FFT ----------------
__global__ __launch_bounds__(256) void conv_kernel(
        float* __restrict__ uty, const cf* __restrict__ tw4,
        const cf* __restrict__ tw8, const cf* __restrict__ kf) {
    __shared__ cf lds[4352];
    int row = blockIdx.x;            // b*DCH + d
    int d = row & (DCH - 1);
    int tid = threadIdx.x;
    float* rp = uty + (size_t)row * SEQL;
    for (int n = tid; n < 2048; n += 256)
        lds[cpad(n)] = *(const float2*)&rp[2*n];
    for (int n = 2048 + tid; n < 4096; n += 256) lds[cpad(n)] = mkc(0.f, 0.f);
    __syncthreads();
    fft_dif(lds, tw4);
    const cf* Hrow = kf + (size_t)d * KH;
    for (int k = tid; k < 2048; k += 256) {
        if (k == 0) {
            cf c0 = lds[cpad(0)];
            float X0 = c0.x + c0.y, X4 = c0.x - c0.y;
            cf H0 = Hrow[0], H4 = Hrow[4096];
            cf Y0 = mkc(X0 * H0.x, X0 * H0.y);
            cf Y4 = mkc(X4 * H4.x, X4 * H4.y);
            cf S  = cadd(Y0, Y4), Dd = csub(Y0, Y4);
            lds[cpad(0)] = addi(S, Dd);                  // Z0 = S + i*D
            int s2 = cpad(drev(2048));
            cf c2 = lds[s2];
            cf Y2 = cmul(cconjf(c2), Hrow[2048]);        // X[2048] = conj(C[2048])
            lds[s2] = mkc(2.f * Y2.x, -2.f * Y2.y);      // Z[2048] = 2*conj(Y)
        } else {
            int kk = 4096 - k;
            int sk = cpad(drev(k)), skk = cpad(drev(kk));
            cf ck = lds[sk], ckk = lds[skk];
            cf cc = cconjf(ckk);
            cf E  = mkc(0.5f*(ck.x+cc.x), 0.5f*(ck.y+cc.y));
            cf Dd = csub(ck, cc);
            cf O  = mkc(0.5f*Dd.y, -0.5f*Dd.x);
            cf wv = tw8[k];
            cf Xk  = cadd(E, cmul(wv, O));
            cf wp  = mkc(-wv.x, wv.y);
            cf Xkk = cadd(cconjf(E), cmul(wp, cconjf(O)));
            cf Yk  = cmul(Xk,  Hrow[k]);
            cf Ykk = cmul(Xkk, Hrow[kk]);
            cf cy = cconjf(Ykk);
            cf S  = cadd(Yk, cy), D2 = csub(Yk, cy);
            cf Zk = addi(S, cmul(cconjf(wv), D2));
            cf cy2 = cconjf(Yk);
            cf S2  = cadd(Ykk, cy2), D3 = csub(Ykk, cy2);
            cf Zkk = subi(S2, cmul(wv, D3));
            lds[sk] = Zk; lds[skk] = Zkk;
        }
    }
    __syncthreads();
    fft_dit_inv(lds, tw4);
    for (int n = tid; n < 2048; n += 256) {
        cf v = lds[cpad(n)];
        *(float2*)&rp[2*n] = v;                          // y[2n], y[2n+1]
    }
}

// ---------------- bf16 MFMA GEMM: out = y^T * (u @ pw^T + pb) + u ----------------
__device__ __forceinline__ unsigned bf16rne(float x){
    unsigned u = __float_as_uint(x);
    return (u + 0x7fffu + ((u >> 16) & 1u)) >> 16;
}
__device__ __forceinline__ unsigned pack2bf(float a, float b){
    return bf16rne(a) | (bf16rne(b) << 16);
}

typedef __attribute__((ext_vector_type(8))) short short8;
typedef __attribute__((ext_vector_type(4))) float f32x4;

__global__ __launch_bounds__(256, 2) void gemm_mfma_kernel(
        const float* __restrict__ u, const float* __restrict__ pw,
        const float* __restrict__ pb, const float* __restrict__ y,
        float* __restrict__ out) {
    __shared__ char lds_raw[34816];
    char* As = lds_raw;                 // [128][32] bf16, XOR-swizzled, 8 KB
    char* Bs = lds_raw + 8192;          // [128][32] bf16, 8 KB
    float (*ysc)[132] = (float(*)[132])lds_raw;   // epilogue reuse: [64][132] f32

    const int tid  = threadIdx.x;
    const int lane = tid & 63;
    const int wid  = tid >> 6;
    const int wr   = wid >> 1;          // wave row  (0..1) -> 64 m-rows
    const int wc   = wid & 1;           // wave col  (0..1) -> 64 n-cols
    const int n0   = blockIdx.x * 128;
    const int m0   = blockIdx.y * 128;

    f32x4 acc[4][4] = {};
    float4 ra[4], rb[4];

    // staging geometry: A-tile 128x32 f32 = 1024 float4; 4 per thread
    int s_row[4], s_f4[4];
#pragma unroll
    for (int j = 0; j < 4; ++j) {
        int idx = j * 256 + tid;
        s_row[j] = idx >> 3;            // 0..127
        s_f4[j]  = idx & 7;             // 0..7  (float4 within 32-col row)
    }

#define LOADT(kt)                                                                     \
    {                                                                                 \
        _Pragma("unroll")                                                             \
        for (int j = 0; j < 4; ++j) {                                                 \
            ra[j] = *(const float4*)&u [(size_t)(m0 + s_row[j]) * DCH + (kt) + s_f4[j] * 4]; \
            rb[j] = *(const float4*)&pw[(size_t)(n0 + s_row[j]) * DCH + (kt) + s_f4[j] * 4]; \
        }                                                                             \
    }
#define WRITET()                                                                      \
    {                                                                                 \
        _Pragma("unroll")                                                             \
        for (int j = 0; j < 4; ++j) {                                                 \
            int off = (s_row[j] * 64 + s_f4[j] * 8) ^ ((s_row[j] & 3) << 4);          \
            uint2 pa, pbv;                                                            \
            pa.x  = pack2bf(ra[j].x, ra[j].y);  pa.y  = pack2bf(ra[j].z, ra[j].w);    \
            pbv.x = pack2bf(rb[j].x, rb[j].y);  pbv.y = pack2bf(rb[j].z, rb[j].w);    \
            *(uint2*)(As + off) = pa;                                                 \
            *(uint2*)(Bs + off) = pbv;                                                \
        }                                                                             \
    }

    LOADT(0);
    WRITET();
    __syncthreads();

    for (int t = 0; t < 32; ++t) {
        if (t < 31) LOADT((t + 1) * 32);
        short8 af[4], bf[4];
#pragma unroll
        for (int f = 0; f < 4; ++f) {
            int rowA = wr * 64 + f * 16 + (lane & 15);
            int rowB = wc * 64 + f * 16 + (lane & 15);
            int offA = (rowA * 64 + ((lane >> 4) * 16)) ^ ((rowA & 3) << 4);
            int offB = (rowB * 64 + ((lane >> 4) * 16)) ^ ((rowB & 3) << 4);
            af[f] = *(short8*)(As + offA);
            bf[f] = *(short8*)(Bs + offB);
        }
#pragma unroll
        for (int mf = 0; mf < 4; ++mf)
#pragma unroll
            for (int nf = 0; nf < 4; ++nf)
                acc[mf][nf] = __builtin_amdgcn_mfma_f32_16x16x32_bf16(
                    af[mf], bf[nf], acc[mf][nf], 0, 0, 0);
        __syncthreads();
        if (t < 31) {
            WRITET();
        }
        __syncthreads();
    }

    // ---- fused epilogue: out = y^T * (acc + pb) + u ----
    const int b  = m0 >> 12;            // m0 / SEQL
    const int l0 = m0 & (SEQL - 1);
    float pbv[4];
#pragma unroll
    for (int nf = 0; nf < 4; ++nf)
        pbv[nf] = pb[n0 + wc * 64 + nf * 16 + (lane & 15)];

    for (int c = 0; c < 2; ++c) {       // two 64-l-row chunks
        __syncthreads();
        // stage ysc[l_local][n_local]: y is (B,D,L); coalesced along l
#pragma unroll
        for (int j = 0; j < 8; ++j) {
            int idx = j * 256 + tid;    // 2048 float4 = 128 dn x 16 lf4
            int dn  = idx >> 4;
            int lf4 = idx & 15;
            float4 vy = *(const float4*)&y[(((size_t)(b * DCH + n0 + dn)) << 12) + l0 + c * 64 + lf4 * 4];
            ysc[lf4 * 4 + 0][dn] = vy.x;
            ysc[lf4 * 4 + 1][dn] = vy.y;
            ysc[lf4 * 4 + 2][dn] = vy.z;
            ysc[lf4 * 4 + 3][dn] = vy.w;
        }
        __syncthreads();
        if (wr == c) {
#pragma unroll
            for (int mf = 0; mf < 4; ++mf)
#pragma unroll
                for (int i = 0; i < 4; ++i) {
                    int lrow = mf * 16 + (lane >> 4) * 4 + i;   // 0..63 within chunk
                    int m = m0 + c * 64 + lrow;
#pragma unroll
                    for (int nf = 0; nf < 4; ++nf) {
                        int nl = wc * 64 + nf * 16 + (lane & 15);
                        int n = n0 + nl;
                        float proj = acc[mf][nf][i] + pbv[nf];
                        out[(size_t)m * DCH + n] = ysc[lrow][nl] * proj + u[(size_t)m * DCH + n];
                    }
                }
        }
    }
#undef LOADT
#undef WRITET
}

extern "C" void kernel_launch(void* const* d_in, const int* in_sizes, int n_in,
                              void* d_out, int out_size, void* d_ws, size_t ws_size,
                              hipStream_t stream) {
    const float* u  = (const float*)d_in[0];
    const float* z  = (const float*)d_in[1];
    const float* w1 = (const float*)d_in[2];
    const float* b1 = (const float*)d_in[3];
    const float* w2 = (const float*)d_in[4];
    const float* b2 = (const float*)d_in[5];
    const float* pw = (const float*)d_in[6];
    const float* pb = (const float*)d_in[7];
    float* out = (float*)d_out;

    float* h   = (float*)d_ws;                           // 256 KB
    float* uty = (float*)((char*)d_ws + 262144);         // 64 MB
    // scratch inside d_out (fully overwritten by gemm at the end):
    cf* kf  = (cf*)d_out;                                // 1024*4097*8B = 33.5 MB
    cf* tw4 = (cf*)((char*)d_out + (40u << 20));         // 32 KB
    cf* tw8 = tw4 + 4096;                                // 32 KB

    twiddle_init<<<dim3(16), dim3(256), 0, stream>>>(tw4, tw8);
    mlp_kernel<<<dim3(16), dim3(256), 0, stream>>>(z, w1, b1, h);
    transpose_kernel<<<dim3(SEQL / 32, DCH / 32, BATCH), dim3(32, 8), 0, stream>>>(u, uty);
    filt_fft_kernel<<<dim3(DCH), dim3(256), 0, stream>>>(h, w2, b2, tw4, tw8, kf);
    conv_kernel<<<dim3(BATCH * DCH), dim3(256), 0, stream>>>(uty, tw4, tw8, kf);
    gemm_mfma_kernel<<<dim3(DCH / 128, (BATCH * SEQL) / 128), dim3(256), 0, stream>>>(u, pw, pb, uty, out);
}

// Round 4
// 280.451 us; speedup vs baseline: 6.1650x; 1.1874x over previous
//
#include <hip/hip_runtime.h>
#include <hip/hip_bf16.h>

#define SEQL 4096
#define DCH  1024
#define BATCH 4
#define NC   4096        // complex FFT length (carries real length-8192 signal)
#define KH   4097        // stored half-spectrum entries per channel

typedef float2 cf;
__device__ __forceinline__ cf mkc(float x, float y){ return make_float2(x,y); }
__device__ __forceinline__ cf cadd(cf a, cf b){ return mkc(a.x+b.x, a.y+b.y); }
__device__ __forceinline__ cf csub(cf a, cf b){ return mkc(a.x-b.x, a.y-b.y); }
__device__ __forceinline__ cf cmul(cf a, cf b){ return mkc(a.x*b.x - a.y*b.y, a.x*b.y + a.y*b.x); }
__device__ __forceinline__ cf cconjf(cf a){ return mkc(a.x, -a.y); }
__device__ __forceinline__ cf addi(cf a, cf b){ return mkc(a.x - b.y, a.y + b.x); }  // a + i*b
__device__ __forceinline__ cf subi(cf a, cf b){ return mkc(a.x + b.y, a.y - b.x); }  // a - i*b
__device__ __forceinline__ int cpad(int i){ return i + (i >> 4); }                   // +1 cplx per 16
__device__ __forceinline__ int drev(int i){                                          // reverse 6 base-4 digits
    return ((i>>10)&3) | (((i>>8)&3)<<2) | (((i>>6)&3)<<4)
         | (((i>>4)&3)<<6) | (((i>>2)&3)<<8) | ((i&3)<<10);
}

// ---------------- twiddle tables ----------------
__global__ __launch_bounds__(256) void twiddle_init(cf* __restrict__ tw4, cf* __restrict__ tw8){
    int i = blockIdx.x*256 + threadIdx.x;   // 4096 total
    const double TWO_PI = 6.283185307179586476925286766559;
    double a4 = -TWO_PI * (double)i / 4096.0;
    double a8 = -TWO_PI * (double)i / 8192.0;
    tw4[i] = mkc((float)cos(a4), (float)sin(a4));
    tw8[i] = mkc((float)cos(a8), (float)sin(a8));
}

// ---------------- forward radix-4 DIF: natural in -> digit-reversed out ----------------
__device__ void fft_dif(cf* lds, const cf* __restrict__ tw){
    const int tid = threadIdx.x;
#pragma unroll
    for (int p = 0; p < 4; ++p) {
        const int lm = 10 - 2*p;          // log2(m): 10,8,6,4
        const int m  = 1 << lm;
        const int step = 1024 >> lm;
#pragma unroll
        for (int it = 0; it < 4; ++it) {
            int j = tid + (it << 8);
            int k = j & (m-1);
            int g = j >> lm;
            int i0 = (g << (lm+2)) + k;
            cf x0 = lds[cpad(i0)];
            cf x1 = lds[cpad(i0+m)];
            cf x2 = lds[cpad(i0+2*m)];
            cf x3 = lds[cpad(i0+3*m)];
            cf b0 = cadd(x0,x2), b1 = csub(x0,x2);
            cf b2 = cadd(x1,x3), b3 = csub(x1,x3);
            cf u0 = cadd(b0,b2);
            cf u2 = csub(b0,b2);
            cf u1 = subi(b1,b3);
            cf u3 = addi(b1,b3);
            int t1 = k*step;
            lds[cpad(i0)]     = u0;
            lds[cpad(i0+m)]   = cmul(u1, tw[t1]);
            lds[cpad(i0+2*m)] = cmul(u2, tw[2*t1]);
            lds[cpad(i0+3*m)] = cmul(u3, tw[3*t1]);
        }
        __syncthreads();
    }
    // fused m=4 and m=1 passes: each thread owns contiguous 16-complex chunk [16t,16t+16)
    {
        int base = 17*tid;   // cpad(16t) = 17t, contiguous for 16 entries
        cf v[16];
#pragma unroll
        for (int j=0;j<16;++j) v[j] = lds[base+j];
#pragma unroll
        for (int j=0;j<4;++j){   // m=4, L=16, k=j
            cf x0=v[j], x1=v[j+4], x2=v[j+8], x3=v[j+12];
            cf b0=cadd(x0,x2), b1=csub(x0,x2), b2=cadd(x1,x3), b3=csub(x1,x3);
            cf u0=cadd(b0,b2), u2=csub(b0,b2), u1=subi(b1,b3), u3=addi(b1,b3);
            v[j]    = u0;
            v[j+4]  = cmul(u1, tw[256*j]);
            v[j+8]  = cmul(u2, tw[512*j]);
            v[j+12] = cmul(u3, tw[768*j]);
        }
#pragma unroll
        for (int c=0;c<4;++c){   // m=1, L=4, twiddle-free
            cf x0=v[4*c], x1=v[4*c+1], x2=v[4*c+2], x3=v[4*c+3];
            cf b0=cadd(x0,x2), b1=csub(x0,x2), b2=cadd(x1,x3), b3=csub(x1,x3);
            v[4*c]   = cadd(b0,b2);
            v[4*c+1] = subi(b1,b3);
            v[4*c+2] = csub(b0,b2);
            v[4*c+3] = addi(b1,b3);
        }
#pragma unroll
        for (int j=0;j<16;++j) lds[base+j] = v[j];
        __syncthreads();
    }
}

// ---------------- inverse radix-4 DIT: digit-reversed in -> natural out (unscaled) ----------------
__device__ void fft_dit_inv(cf* lds, const cf* __restrict__ tw){
    const int tid = threadIdx.x;
    {   // fused m=1 and m=4 passes
        int base = 17*tid;
        cf v[16];
#pragma unroll
        for (int j=0;j<16;++j) v[j] = lds[base+j];
#pragma unroll
        for (int c=0;c<4;++c){   // m=1
            cf a0=v[4*c], a1=v[4*c+1], a2=v[4*c+2], a3=v[4*c+3];
            cf b0=cadd(a0,a2), b1=csub(a0,a2), b2=cadd(a1,a3), b3=csub(a1,a3);
            v[4*c]   = cadd(b0,b2);
            v[4*c+1] = addi(b1,b3);
            v[4*c+2] = csub(b0,b2);
            v[4*c+3] = subi(b1,b3);
        }
#pragma unroll
        for (int j=0;j<4;++j){   // m=4, L=16, k=j, conj twiddles applied to inputs
            cf a0=v[j];
            cf a1=cmul(v[j+4],  cconjf(tw[256*j]));
            cf a2=cmul(v[j+8],  cconjf(tw[512*j]));
            cf a3=cmul(v[j+12], cconjf(tw[768*j]));
            cf b0=cadd(a0,a2), b1=csub(a0,a2), b2=cadd(a1,a3), b3=csub(a1,a3);
            v[j]    = cadd(b0,b2);
            v[j+4]  = addi(b1,b3);
            v[j+8]  = csub(b0,b2);
            v[j+12] = subi(b1,b3);
        }
#pragma unroll
        for (int j=0;j<16;++j) lds[base+j] = v[j];
        __syncthreads();
    }
#pragma unroll
    for (int p = 0; p < 4; ++p) {
        const int lm = 4 + 2*p;           // m = 16,64,256,1024
        const int m  = 1 << lm;
        const int step = 1024 >> lm;
#pragma unroll
        for (int it = 0; it < 4; ++it) {
            int j = tid + (it << 8);
            int k = j & (m-1);
            int g = j >> lm;
            int i0 = (g << (lm+2)) + k;
            int t1 = k*step;
            cf a0 = lds[cpad(i0)];
            cf a1 = cmul(lds[cpad(i0+m)],   cconjf(tw[t1]));
            cf a2 = cmul(lds[cpad(i0+2*m)], cconjf(tw[2*t1]));
            cf a3 = cmul(lds[cpad(i0+3*m)], cconjf(tw[3*t1]));
            cf b0=cadd(a0,a2), b1=csub(a0,a2), b2=cadd(a1,a3), b3=csub(a1,a3);
            lds[cpad(i0)]     = cadd(b0,b2);
            lds[cpad(i0+m)]   = addi(b1,b3);
            lds[cpad(i0+2*m)] = csub(b0,b2);
            lds[cpad(i0+3*m)] = subi(b1,b3);
        }
        __syncthreads();
    }
}

// ---------------- MLP: h[l][16] ----------------
__global__ __launch_bounds__(256) void mlp_kernel(
        const float* __restrict__ z, const float* __restrict__ w1,
        const float* __restrict__ b1, float* __restrict__ h) {
    int l = blockIdx.x * blockDim.x + threadIdx.x;
    if (l >= SEQL) return;
    float pe0 = z[l * 3 + 0], pe1 = z[l * 3 + 1], pe2 = z[l * 3 + 2];
#pragma unroll
    for (int j = 0; j < 16; ++j) {
        float v = pe0 * w1[j * 3 + 0] + pe1 * w1[j * 3 + 1] + pe2 * w1[j * 3 + 2] + b1[j];
        h[l * 16 + j] = v > 0.f ? v : 0.f;
    }
}

// ---------------- transpose u (B,L,D) -> ut (B,D,L) ----------------
__global__ __launch_bounds__(256) void transpose_kernel(
        const float* __restrict__ u, float* __restrict__ ut) {
    __shared__ float tile[32][33];
    int b = blockIdx.z;
    int l0 = blockIdx.x * 32;
    int d0 = blockIdx.y * 32;
    int tx = threadIdx.x, ty = threadIdx.y;  // 32 x 8
    const float* up = u + (size_t)b * SEQL * DCH;
#pragma unroll
    for (int i = 0; i < 32; i += 8)
        tile[ty + i][tx] = up[(size_t)(l0 + ty + i) * DCH + d0 + tx];
    __syncthreads();
    float* utp = ut + (size_t)b * DCH * SEQL;
#pragma unroll
    for (int i = 0; i < 32; i += 8)
        utp[(size_t)(d0 + ty + i) * SEQL + l0 + tx] = tile[tx][ty + i];
}

// ---------------- filter row -> packed FFT -> H[d][0..4096] (scaled 1/8192) ----------------
__global__ __launch_bounds__(256) void filt_fft_kernel(
        const float* __restrict__ h, const float* __restrict__ w2,
        const float* __restrict__ b2, const cf* __restrict__ tw4,
        const cf* __restrict__ tw8, cf* __restrict__ kf) {
    __shared__ cf lds[4352];
    int d = blockIdx.x;
    int tid = threadIdx.x;
    float w[16];
#pragma unroll
    for (int j = 0; j < 16; ++j) w[j] = w2[d * 16 + j];
    float bb = b2[d];
    for (int n = tid; n < 2048; n += 256) {
        const float* h0 = h + (size_t)(2*n) * 16;
        float f0 = bb, f1 = bb;
#pragma unroll
        for (int j = 0; j < 16; ++j) { f0 += h0[j] * w[j]; f1 += h0[16 + j] * w[j]; }
        lds[cpad(n)] = mkc(f0, f1);
    }
    for (int n = 2048 + tid; n < 4096; n += 256) lds[cpad(n)] = mkc(0.f, 0.f);
    __syncthreads();
    fft_dif(lds, tw4);
    const float s = 1.f / 8192.f;
    cf* Hrow = kf + (size_t)d * KH;
    for (int k = tid; k < 2048; k += 256) {
        if (k == 0) {
            cf c0 = lds[cpad(0)];
            Hrow[0]    = mkc((c0.x + c0.y) * s, 0.f);
            Hrow[4096] = mkc((c0.x - c0.y) * s, 0.f);
            cf c2 = lds[cpad(drev(2048))];
            Hrow[2048] = mkc(c2.x * s, -c2.y * s);
        } else {
            int kk = 4096 - k;
            cf ck  = lds[cpad(drev(k))];
            cf ckk = lds[cpad(drev(kk))];
            cf cc = cconjf(ckk);
            cf E  = mkc(0.5f*(ck.x+cc.x), 0.5f*(ck.y+cc.y));
            cf Dd = csub(ck, cc);
            cf O  = mkc(0.5f*Dd.y, -0.5f*Dd.x);          // -i/2 * (ck - conj(ckk))
            cf wv = tw8[k];
            cf Xk  = cadd(E, cmul(wv, O));
            cf wp  = mkc(-wv.x, wv.y);                   // -conj(w) = W^(4096-k)
            cf Xkk = cadd(cconjf(E), cmul(wp, cconjf(O)));
            Hrow[k]  = mkc(Xk.x * s, Xk.y * s);
            Hrow[kk] = mkc(Xkk.x * s, Xkk.y * s);
        }
    }
}

// ---------------- conv: packed fwd FFT -> spectral multiply -> packed inv FFT ----------------
__global__ __launch_bounds__(256) void conv_kernel(
        float* __restrict__ uty, const cf* __restrict__ tw4,
        const cf* __restrict__ tw8, const cf* __restrict__ kf) {
    __shared__ cf lds[4352];
    int row = blockIdx.x;            // b*DCH + d
    int d = row & (DCH - 1);
    int tid = threadIdx.x;
    float* rp = uty + (size_t)row * SEQL;
    for (int n = tid; n < 2048; n += 256)
        lds[cpad(n)] = *(const float2*)&rp[2*n];
    for (int n = 2048 + tid; n < 4096; n += 256) lds[cpad(n)] = mkc(0.f, 0.f);
    __syncthreads();
    fft_dif(lds, tw4);
    const cf* Hrow = kf + (size_t)d * KH;
    for (int k = tid; k < 2048; k += 256) {
        if (k == 0) {
            cf c0 = lds[cpad(0)];
            float X0 = c0.x + c0.y, X4 = c0.x - c0.y;
            cf H0 = Hrow[0], H4 = Hrow[4096];
            cf Y0 = mkc(X0 * H0.x, X0 * H0.y);
            cf Y4 = mkc(X4 * H4.x, X4 * H4.y);
            cf S  = cadd(Y0, Y4), Dd = csub(Y0, Y4);
            lds[cpad(0)] = addi(S, Dd);                  // Z0 = S + i*D
            int s2 = cpad(drev(2048));
            cf c2 = lds[s2];
            cf Y2 = cmul(cconjf(c2), Hrow[2048]);        // X[2048] = conj(C[2048])
            lds[s2] = mkc(2.f * Y2.x, -2.f * Y2.y);      // Z[2048] = 2*conj(Y)
        } else {
            int kk = 4096 - k;
            int sk = cpad(drev(k)), skk = cpad(drev(kk));
            cf ck = lds[sk], ckk = lds[skk];
            cf cc = cconjf(ckk);
            cf E  = mkc(0.5f*(ck.x+cc.x), 0.5f*(ck.y+cc.y));
            cf Dd = csub(ck, cc);
            cf O  = mkc(0.5f*Dd.y, -0.5f*Dd.x);
            cf wv = tw8[k];
            cf Xk  = cadd(E, cmul(wv, O));
            cf wp  = mkc(-wv.x, wv.y);
            cf Xkk = cadd(cconjf(E), cmul(wp, cconjf(O)));
            cf Yk  = cmul(Xk,  Hrow[k]);
            cf Ykk = cmul(Xkk, Hrow[kk]);
            cf cy = cconjf(Ykk);
            cf S  = cadd(Yk, cy), D2 = csub(Yk, cy);
            cf Zk = addi(S, cmul(cconjf(wv), D2));
            cf cy2 = cconjf(Yk);
            cf S2  = cadd(Ykk, cy2), D3 = csub(Ykk, cy2);
            cf Zkk = subi(S2, cmul(wv, D3));
            lds[sk] = Zk; lds[skk] = Zkk;
        }
    }
    __syncthreads();
    fft_dit_inv(lds, tw4);
    for (int n = tid; n < 2048; n += 256) {
        cf v = lds[cpad(n)];
        *(float2*)&rp[2*n] = v;                          // y[2n], y[2n+1]
    }
}

// ---------------- bf16 MFMA GEMM: out = y^T * (u @ pw^T + pb) + u ----------------
__device__ __forceinline__ unsigned pack2bf(float a, float b){
    unsigned r;
    asm("v_cvt_pk_bf16_f32 %0, %1, %2" : "=v"(r) : "v"(a), "v"(b));
    return r;   // lo = bf16(a), hi = bf16(b)
}

typedef __attribute__((ext_vector_type(8))) short short8;
typedef __attribute__((ext_vector_type(4))) float f32x4;

__global__ __launch_bounds__(256, 3) void gemm_mfma_kernel(
        const float* __restrict__ u, const float* __restrict__ pw,
        const float* __restrict__ pb, const float* __restrict__ y,
        float* __restrict__ out) {
    // double-buffered bf16 tiles: buf0 @0 (A) / @8192 (B), buf1 @16384 / @24576
    // epilogue overlays the whole region as ysc[64][132] f32 (33792 B)
    __shared__ char lds_raw[34816];
    float (*ysc)[132] = (float(*)[132])lds_raw;

    const int tid  = threadIdx.x;
    const int lane = tid & 63;
    const int wid  = tid >> 6;
    const int wr   = wid >> 1;          // wave row (0..1) -> 64 m-rows
    const int wc   = wid & 1;           // wave col (0..1) -> 64 n-cols
    const int m0   = blockIdx.x * 128;  // m-major grid: same-m blocks share an XCD
    const int n0   = blockIdx.y * 128;

    f32x4 acc[4][4] = {};
    float4 ra[4], rb[4];

    // staging geometry: tile 128x32 f32 = 1024 float4; 4 per thread
    int s_row[4], s_f4[4];
#pragma unroll
    for (int j = 0; j < 4; ++j) {
        int idx = j * 256 + tid;
        s_row[j] = idx >> 3;            // 0..127
        s_f4[j]  = idx & 7;             // 0..7
    }

#define LOADT(kt)                                                                     \
    {                                                                                 \
        _Pragma("unroll")                                                             \
        for (int j = 0; j < 4; ++j) {                                                 \
            ra[j] = *(const float4*)&u [(size_t)(m0 + s_row[j]) * DCH + (kt) + s_f4[j] * 4]; \
            rb[j] = *(const float4*)&pw[(size_t)(n0 + s_row[j]) * DCH + (kt) + s_f4[j] * 4]; \
        }                                                                             \
    }
#define WRITET(base)                                                                  \
    {                                                                                 \
        _Pragma("unroll")                                                             \
        for (int j = 0; j < 4; ++j) {                                                 \
            int off = (base) + ((s_row[j] * 64 + s_f4[j] * 8) ^ ((s_row[j] & 3) << 4)); \
            uint2 pa, pbv2;                                                           \
            pa.x   = pack2bf(ra[j].x, ra[j].y);  pa.y   = pack2bf(ra[j].z, ra[j].w);  \
            pbv2.x = pack2bf(rb[j].x, rb[j].y);  pbv2.y = pack2bf(rb[j].z, rb[j].w);  \
            *(uint2*)(lds_raw + off)        = pa;                                     \
            *(uint2*)(lds_raw + off + 8192) = pbv2;                                   \
        }                                                                             \
    }

    LOADT(0);
    WRITET(0);          // tile 0 -> buf0
    LOADT(32);          // tile 1 -> regs
    __syncthreads();

    for (int t = 0; t < 32; ++t) {
        const int cur = (t & 1) << 14;          // 0 or 16384
        short8 af[4], bf[4];
#pragma unroll
        for (int f = 0; f < 4; ++f) {
            int rowA = wr * 64 + f * 16 + (lane & 15);
            int rowB = wc * 64 + f * 16 + (lane & 15);
            int offA = cur + ((rowA * 64 + ((lane >> 4) * 16)) ^ ((rowA & 3) << 4));
            int offB = cur + 8192 + ((rowB * 64 + ((lane >> 4) * 16)) ^ ((rowB & 3) << 4));
            af[f] = *(short8*)(lds_raw + offA);
            bf[f] = *(short8*)(lds_raw + offB);
        }
        if (t < 31) WRITET(cur ^ 16384);        // tile t+1 -> other buffer
        if (t < 30) LOADT((t + 2) * 32);        // prefetch tile t+2 -> regs
#pragma unroll
        for (int mf = 0; mf < 4; ++mf)
#pragma unroll
            for (int nf = 0; nf < 4; ++nf)
                acc[mf][nf] = __builtin_amdgcn_mfma_f32_16x16x32_bf16(
                    af[mf], bf[nf], acc[mf][nf], 0, 0, 0);
        __syncthreads();
    }

    // ---- fused epilogue: out = y^T * (acc + pb) + u ----
    const int b  = m0 >> 12;            // m0 / SEQL
    const int l0 = m0 & (SEQL - 1);
    float pbv[4];
#pragma unroll
    for (int nf = 0; nf < 4; ++nf)
        pbv[nf] = pb[n0 + wc * 64 + nf * 16 + (lane & 15)];

    for (int c = 0; c < 2; ++c) {       // two 64-l-row chunks
        __syncthreads();
        // stage ysc[l_local][n_local]: y is (B,D,L); coalesced along l
#pragma unroll
        for (int j = 0; j < 8; ++j) {
            int idx = j * 256 + tid;    // 2048 float4 = 128 dn x 16 lf4
            int dn  = idx >> 4;
            int lf4 = idx & 15;
            float4 vy = *(const float4*)&y[(((size_t)(b * DCH + n0 + dn)) << 12) + l0 + c * 64 + lf4 * 4];
            ysc[lf4 * 4 + 0][dn] = vy.x;
            ysc[lf4 * 4 + 1][dn] = vy.y;
            ysc[lf4 * 4 + 2][dn] = vy.z;
            ysc[lf4 * 4 + 3][dn] = vy.w;
        }
        __syncthreads();
        if (wr == c) {
#pragma unroll
            for (int mf = 0; mf < 4; ++mf)
#pragma unroll
                for (int i = 0; i < 4; ++i) {
                    int lrow = mf * 16 + (lane >> 4) * 4 + i;   // 0..63 within chunk
                    int m = m0 + c * 64 + lrow;
#pragma unroll
                    for (int nf = 0; nf < 4; ++nf) {
                        int nl = wc * 64 + nf * 16 + (lane & 15);
                        int n = n0 + nl;
                        float proj = acc[mf][nf][i] + pbv[nf];
                        out[(size_t)m * DCH + n] = ysc[lrow][nl] * proj + u[(size_t)m * DCH + n];
                    }
                }
        }
    }
#undef LOADT
#undef WRITET
}

extern "C" void kernel_launch(void* const* d_in, const int* in_sizes, int n_in,
                              void* d_out, int out_size, void* d_ws, size_t ws_size,
                              hipStream_t stream) {
    const float* u  = (const float*)d_in[0];
    const float* z  = (const float*)d_in[1];
    const float* w1 = (const float*)d_in[2];
    const float* b1 = (const float*)d_in[3];
    const float* w2 = (const float*)d_in[4];
    const float* b2 = (const float*)d_in[5];
    const float* pw = (const float*)d_in[6];
    const float* pb = (const float*)d_in[7];
    float* out = (float*)d_out;

    float* h   = (float*)d_ws;                           // 256 KB
    float* uty = (float*)((char*)d_ws + 262144);         // 64 MB
    // scratch inside d_out (fully overwritten by gemm at the end):
    cf* kf  = (cf*)d_out;                                // 1024*4097*8B = 33.5 MB
    cf* tw4 = (cf*)((char*)d_out + (40u << 20));         // 32 KB
    cf* tw8 = tw4 + 4096;                                // 32 KB

    twiddle_init<<<dim3(16), dim3(256), 0, stream>>>(tw4, tw8);
    mlp_kernel<<<dim3(16), dim3(256), 0, stream>>>(z, w1, b1, h);
    transpose_kernel<<<dim3(SEQL / 32, DCH / 32, BATCH), dim3(32, 8), 0, stream>>>(u, uty);
    filt_fft_kernel<<<dim3(DCH), dim3(256), 0, stream>>>(h, w2, b2, tw4, tw8, kf);
    conv_kernel<<<dim3(BATCH * DCH), dim3(256), 0, stream>>>(uty, tw4, tw8, kf);
    gemm_mfma_kernel<<<dim3(128, 8), dim3(256), 0, stream>>>(u, pw, pb, uty, out);
}